// Round 7
// baseline (52.340 us; speedup 1.0000x reference)
//
#include <hip/hip_runtime.h>
#include <math.h>

// B=2, C=64, H=W=128, N=9, KS=3, PAD=1.
// Round 7: attack TA (vector-mem transaction) saturation — r4/r5/r6 all pinned
// at ~41us for k_fused regardless of TLP/ILP because divergent-pixel lane maps
// made every tap load ~64 transactions. Changes:
//   - phase-1 taps: stage 3x18px window (hi+lo) into XOR-swizzled LDS via linear
//     coalesced copies; MFMA B-frags read from LDS (DS pipe, not TA).
//   - phase-2 gather: thread map (p=u>>3, cq=u&7) -> each quad reads contiguous
//     64B of ONE pixel (minimal tx); combine fp32; write bf16 xs[16][584] LDS
//     (73*16B row stride => uniform bank-quad use); MFMA frags from LDS.
// Offset conv stays split-bf16 3-term MFMA (fp32-grade offsets; reference depth
// bilinear is discontinuous at coord 127 and amplifies offset error).
// k map (same for A and B packs; HW k-permutation cancels):
//   k = s*32 + h*8 + e;  t/n = s>>1;  c = (s&1)*32 + h*8 + e.
// C/D: col = lane&15 (pixel), row = h*4+reg. Verified r3-r6.

typedef __attribute__((ext_vector_type(8))) short bf16x8;
typedef __attribute__((ext_vector_type(4))) short s16x4;
typedef __attribute__((ext_vector_type(4))) float f32x4;

#define MFMA16(a, b, c) __builtin_amdgcn_mfma_f32_16x16x32_bf16((a), (b), (c), 0, 0, 0)

__device__ __forceinline__ float bf2f(short v) {
    return __uint_as_float(((unsigned)(unsigned short)v) << 16);
}
__device__ __forceinline__ short f2bf(float f) {
    unsigned u = __float_as_uint(f);
    u = u + 0x7fffu + ((u >> 16) & 1u);
    return (short)(u >> 16);
}

// ---------------- prep: LDS-transpose x -> xT/xTlo; pack wK, wPh, wPl ----------------
__global__ __launch_bounds__(256) void k_prep(const float* __restrict__ x,
                                              const float* __restrict__ w_conv,
                                              const float* __restrict__ w_p,
                                              short* __restrict__ xT,
                                              short* __restrict__ xTlo,
                                              short* __restrict__ wK,
                                              short* __restrict__ wPh,
                                              short* __restrict__ wPl) {
    __shared__ short sH[128][72];
    __shared__ short sL[128][72];
    int bid = blockIdx.x;
    int tid = threadIdx.x;
    if (bid < 256) {
        int p = tid & 127;
        int halfc = tid >> 7;
        int pix0 = bid << 7;
        int b = pix0 >> 14;
        const float* xb = x + (size_t)b * 64 * 16384 + (pix0 & 16383);
#pragma unroll
        for (int cc = 0; cc < 8; ++cc) {
            int c0 = cc * 8 + halfc * 4;
            union { short s[4]; s16x4 v; } hi, lo;
#pragma unroll
            for (int e = 0; e < 4; ++e) {
                float v = xb[(c0 + e) * 16384 + p];
                short hb = f2bf(v);
                hi.s[e] = hb;
                lo.s[e] = f2bf(v - bf2f(hb));
            }
            *reinterpret_cast<s16x4*>(&sH[p][c0]) = hi.v;
            *reinterpret_cast<s16x4*>(&sL[p][c0]) = lo.v;
        }
        __syncthreads();
        short* xTo = xT   + ((size_t)pix0 << 6);
        short* xLo = xTlo + ((size_t)pix0 << 6);
#pragma unroll
        for (int r = 0; r < 4; ++r) {
            int u = (r << 8) + tid;
            int pp = u >> 3, ch8 = u & 7;
            *reinterpret_cast<bf16x8*>(xTo + pp * 64 + ch8 * 8) =
                *reinterpret_cast<const bf16x8*>(&sH[pp][ch8 * 8]);
            *reinterpret_cast<bf16x8*>(xLo + pp * 64 + ch8 * 8) =
                *reinterpret_cast<const bf16x8*>(&sL[pp][ch8 * 8]);
        }
    } else {
        int idx = (bid - 256) * 256 + tid;
        if (idx >= 55296) return;
        if (idx < 36864) {
            int e = idx & 7, o = (idx >> 3) & 63, h = (idx >> 9) & 3, s = idx >> 11;
            int k = s * 32 + h * 8 + e;
            int n = k >> 6, c = k & 63;
            wK[idx] = f2bf(w_conv[o * 576 + c * 9 + n]);
        } else {
            int j = idx - 36864;
            int e = j & 7, m = (j >> 3) & 31, h = (j >> 8) & 3, s = j >> 10;
            int k = s * 32 + h * 8 + e;
            int t = k >> 6, c = k & 63;
            float v = (m < 18) ? w_p[m * 576 + c * 9 + t] : 0.f;
            short hb = f2bf(v);
            wPh[j] = hb;
            wPl[j] = f2bf(v - bf2f(hb));
        }
    }
}

// ---------------- fused: 128 thr = 2 waves on 16 px, TA-minimized ----------------
__global__ __launch_bounds__(128, 2) void k_fused(const short* __restrict__ xT,
                                                  const short* __restrict__ xTlo,
                                                  const short* __restrict__ wPh,
                                                  const short* __restrict__ wPl,
                                                  const short* __restrict__ wK,
                                                  const float* __restrict__ depth,
                                                  const float* __restrict__ b_p,
                                                  float* __restrict__ out) {
    // dynbuf serves two lives: phase-1 window [2][3][20px][64c] swizzled (15360B),
    // then phase-2 xs[16][584] bf16 (18688B).
    __shared__ __align__(16) char dynbuf[18688];
    __shared__ float part1[2][16][20];   // 2560 B
    __shared__ float offs[16][20];       // 1280 B
    __shared__ float pmw[144][8];        // 4608 B
    __shared__ float accred[64][16];     // 4096 B
    __shared__ float obuf[64 * 17];      // 4352 B   total ~35.6 KB -> 4 blocks/CU
    int tid = threadIdx.x;
    int lane = tid & 63;
    int wv = tid >> 6;
    int l15 = lane & 15, h = lane >> 4;
    // XCD band swizzle (bijective: 2048 = 8*256)
    int bid = blockIdx.x;
    int swz = (bid & 7) * 256 + (bid >> 3);
    int pb = swz << 4;
    int b = pb >> 14, i = (pb & 16383) >> 7, j0 = pb & 127;
    const short* xTb  = xT   + ((size_t)b << 20);
    const short* xTlb = xTlo + ((size_t)b << 20);

    // ---- stage 3-row x 18-px window (hi+lo) into swizzled LDS; fully coalesced ----
    for (int u = tid; u < 864; u += 128) {
        int c8 = u & 7;
        int t2 = u >> 3;           // 0..107
        int px = t2 % 18;
        int t3 = t2 / 18;          // 0..5
        int r = t3 % 3;
        int hl = t3 / 3;
        int si = i + r - 1;
        int sj = j0 + px - 1;
        bf16x8 v = {0, 0, 0, 0, 0, 0, 0, 0};
        if ((unsigned)si < 128u && (unsigned)sj < 128u) {
            const short* src = (hl ? xTlb : xTb) + ((size_t)(si * 128 + sj) << 6) + c8 * 8;
            v = *reinterpret_cast<const bf16x8*>(src);
        }
        int dst = (hl * 3 + r) * 2560 + px * 128 + (((c8 ^ (px & 7))) << 4);
        *reinterpret_cast<bf16x8*>(dynbuf + dst) = v;
    }
    __syncthreads();

    // ---- phase 1: offset conv; wave wv = channel half wv; B-frags from LDS ----
    f32x4 acc0 = {0.f, 0.f, 0.f, 0.f}, acc1 = {0.f, 0.f, 0.f, 0.f};
#pragma unroll
    for (int t = 0; t < 9; ++t) {
        int s_ = t * 2 + wv;
        int px = t % 3 + l15;
        int slot = ((wv * 4 + h) ^ (px & 7)) << 4;
        const char* basep = dynbuf + (t / 3) * 2560 + px * 128 + slot;
        bf16x8 bh = *reinterpret_cast<const bf16x8*>(basep);
        bf16x8 bl = *reinterpret_cast<const bf16x8*>(basep + 3 * 2560);
        const short* wh_ = wPh + (size_t)((s_ * 4 + h) * 32 + l15) * 8;
        const short* wl_ = wPl + (size_t)((s_ * 4 + h) * 32 + l15) * 8;
        bf16x8 ah0 = *reinterpret_cast<const bf16x8*>(wh_);
        bf16x8 ah1 = *reinterpret_cast<const bf16x8*>(wh_ + 128);
        bf16x8 al0 = *reinterpret_cast<const bf16x8*>(wl_);
        bf16x8 al1 = *reinterpret_cast<const bf16x8*>(wl_ + 128);
        acc0 = MFMA16(ah0, bh, acc0);
        acc1 = MFMA16(ah1, bh, acc1);
        acc0 = MFMA16(ah0, bl, acc0);
        acc1 = MFMA16(ah1, bl, acc1);
        acc0 = MFMA16(al0, bh, acc0);
        acc1 = MFMA16(al1, bh, acc1);
    }
#pragma unroll
    for (int r = 0; r < 4; ++r) {
        part1[wv][l15][h * 4 + r] = acc0[r];
        int o1 = 16 + h * 4 + r;
        if (o1 < 18) part1[wv][l15][o1] = acc1[r];
    }
    __syncthreads();
    for (int u = tid; u < 288; u += 128) {
        int p = u / 18, o = u % 18;
        offs[p][o] = part1[0][p][o] + part1[1][p][o] + b_p[o];
    }
    __syncthreads();

    // ---- epilogue: depth bilinear -> pmw (exact reference semantics) ----
    const float* db = depth + (b << 14);
    float dctr = db[(i << 7) + j0 + l15];
    int g = (wv << 2) + h;
    for (int n = g; n < 9; n += 8) {
        float offx = offs[l15][n];
        float offy = offs[l15][9 + n];
        float gx = (float)(n / 3 - 1 + i + 1);
        float gy = (float)(n % 3 - 1 + j0 + l15 + 1);
        float p1x = offx + gx, p1y = offy + gy;
        float fx = floorf(p1x), fy = floorf(p1y);
        float qltx = fminf(fmaxf(fx, 0.f), 127.f);
        float qlty = fminf(fmaxf(fy, 0.f), 127.f);
        float qrbx = fminf(fmaxf(fx + 1.f, 0.f), 127.f);
        float qrby = fminf(fmaxf(fy + 1.f, 0.f), 127.f);
        float pxc = fminf(fmaxf(p1x, 0.f), 127.f);
        float pyc = fminf(fmaxf(p1y, 0.f), 127.f);
        float glt = (1.f + (qltx - pxc)) * (1.f + (qlty - pyc));
        float grb = (1.f - (qrbx - pxc)) * (1.f - (qrby - pyc));
        float glb = (1.f + (qltx - pxc)) * (1.f - (qrby - pyc));
        float grt = (1.f - (qrbx - pxc)) * (1.f + (qlty - pyc));
        int ilx = (int)qltx, ily = (int)qlty, irx = (int)qrbx, iry = (int)qrby;
        auto dv = [&](int qx, int qy) -> float {
            return (qx >= 1 && qx <= 128 && qy >= 1 && qy <= 128) ? db[(qx - 1) * 128 + (qy - 1)] : 0.f;
        };
        float dof = glt * dv(ilx, ily) + grb * dv(irx, iry) + glb * dv(ilx, iry) + grt * dv(irx, ily);
        float dd = fabsf(dctr - dof);
        float dwn = expf(-4.f * dd) + 0.25f;
        float mn = expf(-dd);
        float px = offx * dwn + gx;
        float py = offy * dwn + gy;
        float fx2 = floorf(px), fy2 = floorf(py);
        float xltx = fminf(fmaxf(fx2, 0.f), 129.f);
        float xlty = fminf(fmaxf(fy2, 0.f), 129.f);
        float xrbx = fminf(fmaxf(fx2 + 1.f, 0.f), 129.f);
        float xrby = fminf(fmaxf(fy2 + 1.f, 0.f), 129.f);
        float xpxc = fminf(fmaxf(px, 0.f), 129.f);
        float xpyc = fminf(fmaxf(py, 0.f), 129.f);
        float wlt = (1.f + (xltx - xpxc)) * (1.f + (xlty - xpyc));
        float wrb = (1.f - (xrbx - xpxc)) * (1.f - (xrby - xpyc));
        float wlb = (1.f + (xltx - xpxc)) * (1.f - (xrby - xpyc));
        float wrt = (1.f - (xrbx - xpxc)) * (1.f + (xlty - xpyc));
        int jlx = (int)xltx, jly = (int)xlty, jrx = (int)xrbx, jry = (int)xrby;
        float* d = pmw[l15 * 9 + n];
        auto mk = [&](int qx, int qy, float gw, int slot) {
            bool ok = (qx >= 1 && qx <= 128 && qy >= 1 && qy <= 128);
            d[slot] = ok ? gw * mn : 0.f;
            d[slot + 4] = __int_as_float(ok ? ((qx - 1) * 128 + (qy - 1)) : 0);
        };
        mk(jlx, jly, wlt, 0);
        mk(jrx, jry, wrb, 1);
        mk(jlx, jry, wlb, 2);
        mk(jrx, jly, wrt, 3);
    }
    __syncthreads();

    // ---- phase 2a: gather+combine -> xs LDS; quad-coalesced tap loads ----
    // unit u -> (p = u/72, n = (u>>3)%9, cq = u&7); 8 threads of a (p,n) read
    // one pixel's contiguous 128B per tap.
    for (int u = tid; u < 1152; u += 128) {
        int cq = u & 7;
        int t2 = u >> 3;
        int n = t2 % 9;
        int p = t2 / 9;
        const float* ww = pmw[p * 9 + n];
        float4 w4 = *reinterpret_cast<const float4*>(ww);
        int4 o4 = *reinterpret_cast<const int4*>(ww + 4);
        int co = cq * 8;
        bf16x8 t0 = *reinterpret_cast<const bf16x8*>(xTb + ((size_t)o4.x << 6) + co);
        bf16x8 t1 = *reinterpret_cast<const bf16x8*>(xTb + ((size_t)o4.y << 6) + co);
        bf16x8 t2v = *reinterpret_cast<const bf16x8*>(xTb + ((size_t)o4.z << 6) + co);
        bf16x8 t3 = *reinterpret_cast<const bf16x8*>(xTb + ((size_t)o4.w << 6) + co);
        union { short s[8]; bf16x8 v; } res;
#pragma unroll
        for (int e = 0; e < 8; ++e) {
            float f = w4.x * bf2f(t0[e]) + w4.y * bf2f(t1[e]) +
                      w4.z * bf2f(t2v[e]) + w4.w * bf2f(t3[e]);
            res.s[e] = f2bf(f);
        }
        *reinterpret_cast<bf16x8*>(dynbuf + p * 1168 + n * 128 + cq * 16) = res.v;
    }
    __syncthreads();

    // ---- phase 2b: MFMA from LDS frags; wave wv covers n%2==wv ----
    f32x4 A0 = {0.f, 0.f, 0.f, 0.f}, A1 = {0.f, 0.f, 0.f, 0.f};
    f32x4 A2 = {0.f, 0.f, 0.f, 0.f}, A3 = {0.f, 0.f, 0.f, 0.f};
    for (int n = wv; n < 9; n += 2) {
        const char* xr = dynbuf + l15 * 1168 + n * 128 + h * 16;
        bf16x8 f0 = *reinterpret_cast<const bf16x8*>(xr);
        bf16x8 f1 = *reinterpret_cast<const bf16x8*>(xr + 64);
        const short* wk0 = wK + (size_t)((n * 8 + h) * 64 + l15) * 8;
        const short* wk1 = wk0 + 2048;
        A0 = MFMA16(*reinterpret_cast<const bf16x8*>(wk0),       f0, A0);
        A1 = MFMA16(*reinterpret_cast<const bf16x8*>(wk0 + 128), f0, A1);
        A2 = MFMA16(*reinterpret_cast<const bf16x8*>(wk0 + 256), f0, A2);
        A3 = MFMA16(*reinterpret_cast<const bf16x8*>(wk0 + 384), f0, A3);
        A0 = MFMA16(*reinterpret_cast<const bf16x8*>(wk1),       f1, A0);
        A1 = MFMA16(*reinterpret_cast<const bf16x8*>(wk1 + 128), f1, A1);
        A2 = MFMA16(*reinterpret_cast<const bf16x8*>(wk1 + 256), f1, A2);
        A3 = MFMA16(*reinterpret_cast<const bf16x8*>(wk1 + 384), f1, A3);
    }
    // ---- reduce across waves + store ----
    if (wv == 1) {
        float* ar = accred[lane];
        *reinterpret_cast<f32x4*>(ar)      = A0;
        *reinterpret_cast<f32x4*>(ar + 4)  = A1;
        *reinterpret_cast<f32x4*>(ar + 8)  = A2;
        *reinterpret_cast<f32x4*>(ar + 12) = A3;
    }
    __syncthreads();
    if (wv == 0) {
        const float* ar = accred[lane];
#pragma unroll
        for (int r = 0; r < 4; ++r) {
            obuf[(h * 4 + r) * 17 + l15]      = A0[r] + ar[r];
            obuf[(16 + h * 4 + r) * 17 + l15] = A1[r] + ar[4 + r];
            obuf[(32 + h * 4 + r) * 17 + l15] = A2[r] + ar[8 + r];
            obuf[(48 + h * 4 + r) * 17 + l15] = A3[r] + ar[12 + r];
        }
    }
    __syncthreads();
#pragma unroll
    for (int r = 0; r < 8; ++r) {
        int u = (r << 7) + tid;
        int o = u >> 4, p = u & 15;
        out[((size_t)(b * 64 + o) << 14) + (i << 7) + j0 + p] = obuf[o * 17 + p];
    }
}

extern "C" void kernel_launch(void* const* d_in, const int* in_sizes, int n_in,
                              void* d_out, int out_size, void* d_ws, size_t ws_size,
                              hipStream_t stream) {
    (void)in_sizes; (void)n_in; (void)out_size; (void)ws_size;
    const float* x      = (const float*)d_in[0];
    const float* depth  = (const float*)d_in[1];
    const float* w_p    = (const float*)d_in[2];
    const float* b_p    = (const float*)d_in[3];
    const float* w_conv = (const float*)d_in[4];
    float* out = (float*)d_out;

    char* wsb = (char*)d_ws;
    short* xT   = (short*)wsb;                     // 4,194,304 B
    short* xTlo = (short*)(wsb + 4194304);         // 4,194,304 B
    short* wK   = (short*)(wsb + 8388608);         //    73,728 B
    short* wPh  = (short*)(wsb + 8462336);         //    36,864 B
    short* wPl  = (short*)(wsb + 8499200);         //    36,864 B  (total ~8.54 MB)

    hipLaunchKernelGGL(k_prep,  dim3(472),  dim3(256), 0, stream,
                       x, w_conv, w_p, xT, xTlo, wK, wPh, wPl);
    hipLaunchKernelGGL(k_fused, dim3(2048), dim3(128), 0, stream,
                       xT, xTlo, wPh, wPl, wK, depth, b_p, out);
}

// Round 8
// 50.887 us; speedup vs baseline: 1.0286x; 1.0286x over previous
//
#include <hip/hip_runtime.h>
#include <math.h>

// B=2, C=64, H=W=128, N=9, KS=3, PAD=1.
// Round 8: kill the per-block scattered-L2 latency chain (r4-r7 invariant,
// ~30K cycles/block). Offsets are tiny (sigma(off*dwn)~0.3), so all bilinear
// taps fall in a +/-3 px window around the 16-px tile: stage
//   - x hi window  7 rows x 22 cols (19.7KB)
//   - x lo window  3 rows x 18 cols (6.9KB, phase-1 only)
//   - depth window 7 rows x 22 cols (616B)
// with ONE coalesced load wall at kernel entry; every tap afterwards is an LDS
// read. Signed per-tap index keeps a correct global fallback for |off|>=2.
// Phase 2 is register-direct B-frags from the window (no xs staging barrier).
// Offset conv stays split-bf16 3-term MFMA (fp32-grade offsets; the reference
// depth bilinear is discontinuous at coord 127 and amplifies offset error).
// k map (same for A and B packs; HW k-permutation cancels):
//   k = s*32 + h*8 + e;  t/n = s>>1;  c = (s&1)*32 + h*8 + e.
// C/D: col = lane&15 (pixel), row = h*4+reg. Verified r3-r7.

typedef __attribute__((ext_vector_type(8))) short bf16x8;
typedef __attribute__((ext_vector_type(4))) short s16x4;
typedef __attribute__((ext_vector_type(4))) float f32x4;

#define MFMA16(a, b, c) __builtin_amdgcn_mfma_f32_16x16x32_bf16((a), (b), (c), 0, 0, 0)

__device__ __forceinline__ float bf2f(short v) {
    return __uint_as_float(((unsigned)(unsigned short)v) << 16);
}
__device__ __forceinline__ short f2bf(float f) {
    unsigned u = __float_as_uint(f);
    u = u + 0x7fffu + ((u >> 16) & 1u);
    return (short)(u >> 16);
}

// ---------------- prep: LDS-transpose x -> xT/xTlo; pack wK, wPh, wPl ----------------
__global__ __launch_bounds__(256) void k_prep(const float* __restrict__ x,
                                              const float* __restrict__ w_conv,
                                              const float* __restrict__ w_p,
                                              short* __restrict__ xT,
                                              short* __restrict__ xTlo,
                                              short* __restrict__ wK,
                                              short* __restrict__ wPh,
                                              short* __restrict__ wPl) {
    __shared__ short sH[128][72];
    __shared__ short sL[128][72];
    int bid = blockIdx.x;
    int tid = threadIdx.x;
    if (bid < 256) {
        int p = tid & 127;
        int halfc = tid >> 7;
        int pix0 = bid << 7;
        int b = pix0 >> 14;
        const float* xb = x + (size_t)b * 64 * 16384 + (pix0 & 16383);
#pragma unroll
        for (int cc = 0; cc < 8; ++cc) {
            int c0 = cc * 8 + halfc * 4;
            union { short s[4]; s16x4 v; } hi, lo;
#pragma unroll
            for (int e = 0; e < 4; ++e) {
                float v = xb[(c0 + e) * 16384 + p];
                short hb = f2bf(v);
                hi.s[e] = hb;
                lo.s[e] = f2bf(v - bf2f(hb));
            }
            *reinterpret_cast<s16x4*>(&sH[p][c0]) = hi.v;
            *reinterpret_cast<s16x4*>(&sL[p][c0]) = lo.v;
        }
        __syncthreads();
        short* xTo = xT   + ((size_t)pix0 << 6);
        short* xLo = xTlo + ((size_t)pix0 << 6);
#pragma unroll
        for (int r = 0; r < 4; ++r) {
            int u = (r << 8) + tid;
            int pp = u >> 3, ch8 = u & 7;
            *reinterpret_cast<bf16x8*>(xTo + pp * 64 + ch8 * 8) =
                *reinterpret_cast<const bf16x8*>(&sH[pp][ch8 * 8]);
            *reinterpret_cast<bf16x8*>(xLo + pp * 64 + ch8 * 8) =
                *reinterpret_cast<const bf16x8*>(&sL[pp][ch8 * 8]);
        }
    } else {
        int idx = (bid - 256) * 256 + tid;
        if (idx >= 55296) return;
        if (idx < 36864) {
            int e = idx & 7, o = (idx >> 3) & 63, h = (idx >> 9) & 3, s = idx >> 11;
            int k = s * 32 + h * 8 + e;
            int n = k >> 6, c = k & 63;
            wK[idx] = f2bf(w_conv[o * 576 + c * 9 + n]);
        } else {
            int j = idx - 36864;
            int e = j & 7, m = (j >> 3) & 31, h = (j >> 8) & 3, s = j >> 10;
            int k = s * 32 + h * 8 + e;
            int t = k >> 6, c = k & 63;
            float v = (m < 18) ? w_p[m * 576 + c * 9 + t] : 0.f;
            short hb = f2bf(v);
            wPh[j] = hb;
            wPl[j] = f2bf(v - bf2f(hb));
        }
    }
}

// ---------------- fused: 128 thr = 2 waves on 16 px; all taps from LDS window ----------------
__global__ __launch_bounds__(128, 2) void k_fused(const short* __restrict__ xT,
                                                  const short* __restrict__ xTlo,
                                                  const short* __restrict__ wPh,
                                                  const short* __restrict__ wPl,
                                                  const short* __restrict__ wK,
                                                  const float* __restrict__ depth,
                                                  const float* __restrict__ b_p,
                                                  float* __restrict__ out) {
    // layout (bytes):
    //   win    [0,     19712)  x hi window: 154 px (7r x 22c) x 128B, XOR-swizzled
    //   lo     [19712, 26624)  x lo window: 54 px (3r x 18c) x 128B
    //   part1  [26624, 29184)  float[2][16][20]
    //   dwin   [29184, 29824)  float[154] (+pad)
    //   offs   [29824, 31104)  float[16][20]
    //   pmw    [31104, 35712)  per-(p,n): float w[4]; int idx[4]  (idx<0 => global fallback)
    //   accred overlays [19712, 23808)   (lo dead after phase 1)
    //   obuf   overlays [23808, 28160)   (lo+part1 dead after reduce)
    __shared__ __align__(16) char smem[35712];
    short* win   = (short*)smem;
    short* lowin = (short*)(smem + 19712);
    float* part1 = (float*)(smem + 26624);
    float* dwin  = (float*)(smem + 29184);
    float* offs  = (float*)(smem + 29824);
    float* pmw   = (float*)(smem + 31104);
    float* accred = (float*)(smem + 19712);
    float* obuf   = (float*)(smem + 23808);

    int tid = threadIdx.x;
    int lane = tid & 63;
    int wv = tid >> 6;
    int l15 = lane & 15, h = lane >> 4;
    // XCD band swizzle (bijective: 2048 = 8*256)
    int bid = blockIdx.x;
    int swz = (bid & 7) * 256 + (bid >> 3);
    int pb = swz << 4;
    int b = pb >> 14, i = (pb & 16383) >> 7, j0 = pb & 127;
    const short* xTb  = xT   + ((size_t)b << 20);
    const short* xTlb = xTlo + ((size_t)b << 20);
    const float* db = depth + (b << 14);

    // ---- stage everything (one coalesced load wall) ----
    for (int u = tid; u < 1232; u += 128) {           // x hi window
        int c8 = u & 7, px = u >> 3;
        int wr = px / 22, wc = px % 22;
        int r = i - 3 + wr, c = j0 - 3 + wc;
        bf16x8 v = {0, 0, 0, 0, 0, 0, 0, 0};
        if ((unsigned)r < 128u && (unsigned)c < 128u)
            v = *reinterpret_cast<const bf16x8*>(xTb + ((size_t)(r * 128 + c) << 6) + c8 * 8);
        *reinterpret_cast<bf16x8*>((char*)win + px * 128 + ((c8 ^ (px & 7)) << 4)) = v;
    }
    for (int u = tid; u < 432; u += 128) {            // x lo window (phase-1 rows)
        int c8 = u & 7, px = u >> 3;
        int rr = px / 18, cc = px % 18;
        int r = i - 1 + rr, c = j0 - 1 + cc;
        bf16x8 v = {0, 0, 0, 0, 0, 0, 0, 0};
        if ((unsigned)r < 128u && (unsigned)c < 128u)
            v = *reinterpret_cast<const bf16x8*>(xTlb + ((size_t)(r * 128 + c) << 6) + c8 * 8);
        *reinterpret_cast<bf16x8*>((char*)lowin + px * 128 + ((c8 ^ (px & 7)) << 4)) = v;
    }
    for (int u = tid; u < 154; u += 128) {            // depth window
        int wr = u / 22, wc = u % 22;
        int r = i - 3 + wr, c = j0 - 3 + wc;
        dwin[u] = ((unsigned)r < 128u && (unsigned)c < 128u) ? db[r * 128 + c] : 0.f;
    }
    __syncthreads();

    // ---- phase 1: offset conv; wave wv = channel half wv; all frags from LDS ----
    f32x4 acc0 = {0.f, 0.f, 0.f, 0.f}, acc1 = {0.f, 0.f, 0.f, 0.f};
    int sl1 = wv * 4 + h;
#pragma unroll
    for (int t = 0; t < 9; ++t) {
        int s_ = t * 2 + wv;
        int pxh = (t / 3 + 2) * 22 + (l15 + t % 3 + 2);
        int pxl = (t / 3) * 18 + (l15 + t % 3);
        bf16x8 bh = *reinterpret_cast<const bf16x8*>((char*)win + pxh * 128 + ((sl1 ^ (pxh & 7)) << 4));
        bf16x8 bl = *reinterpret_cast<const bf16x8*>((char*)lowin + pxl * 128 + ((sl1 ^ (pxl & 7)) << 4));
        const short* wh_ = wPh + (size_t)((s_ * 4 + h) * 32 + l15) * 8;
        const short* wl_ = wPl + (size_t)((s_ * 4 + h) * 32 + l15) * 8;
        bf16x8 ah0 = *reinterpret_cast<const bf16x8*>(wh_);
        bf16x8 ah1 = *reinterpret_cast<const bf16x8*>(wh_ + 128);
        bf16x8 al0 = *reinterpret_cast<const bf16x8*>(wl_);
        bf16x8 al1 = *reinterpret_cast<const bf16x8*>(wl_ + 128);
        acc0 = MFMA16(ah0, bh, acc0);
        acc1 = MFMA16(ah1, bh, acc1);
        acc0 = MFMA16(ah0, bl, acc0);
        acc1 = MFMA16(ah1, bl, acc1);
        acc0 = MFMA16(al0, bh, acc0);
        acc1 = MFMA16(al1, bh, acc1);
    }
#pragma unroll
    for (int r = 0; r < 4; ++r) {
        part1[wv * 320 + l15 * 20 + h * 4 + r] = acc0[r];
        int o1 = 16 + h * 4 + r;
        if (o1 < 18) part1[wv * 320 + l15 * 20 + o1] = acc1[r];
    }
    __syncthreads();
    for (int u = tid; u < 288; u += 128) {
        int p = u / 18, o = u % 18;
        offs[p * 20 + o] = part1[p * 20 + o] + part1[320 + p * 20 + o] + b_p[o];
    }
    __syncthreads();

    // ---- epilogue: depth bilinear (from dwin) -> pmw (exact reference semantics) ----
    float dctr = dwin[3 * 22 + l15 + 3];
    int g = (wv << 2) + h;
    for (int n = g; n < 9; n += 8) {
        float offx = offs[l15 * 20 + n];
        float offy = offs[l15 * 20 + 9 + n];
        float gx = (float)(n / 3 - 1 + i + 1);
        float gy = (float)(n % 3 - 1 + j0 + l15 + 1);
        float p1x = offx + gx, p1y = offy + gy;
        float fx = floorf(p1x), fy = floorf(p1y);
        float qltx = fminf(fmaxf(fx, 0.f), 127.f);
        float qlty = fminf(fmaxf(fy, 0.f), 127.f);
        float qrbx = fminf(fmaxf(fx + 1.f, 0.f), 127.f);
        float qrby = fminf(fmaxf(fy + 1.f, 0.f), 127.f);
        float pxc = fminf(fmaxf(p1x, 0.f), 127.f);
        float pyc = fminf(fmaxf(p1y, 0.f), 127.f);
        float glt = (1.f + (qltx - pxc)) * (1.f + (qlty - pyc));
        float grb = (1.f - (qrbx - pxc)) * (1.f - (qrby - pyc));
        float glb = (1.f + (qltx - pxc)) * (1.f - (qrby - pyc));
        float grt = (1.f - (qrbx - pxc)) * (1.f + (qlty - pyc));
        int ilx = (int)qltx, ily = (int)qlty, irx = (int)qrbx, iry = (int)qrby;
        auto dv = [&](int qx, int qy) -> float {
            if (qx < 1 || qx > 128 || qy < 1 || qy > 128) return 0.f;
            int r = qx - 1, c = qy - 1;
            int wr = r - (i - 3), wc = c - (j0 - 3);
            if ((unsigned)wr < 7u && (unsigned)wc < 22u) return dwin[wr * 22 + wc];
            return db[r * 128 + c];   // ultra-rare fallback
        };
        float dof = glt * dv(ilx, ily) + grb * dv(irx, iry) + glb * dv(ilx, iry) + grt * dv(irx, ily);
        float dd = fabsf(dctr - dof);
        float dwn = expf(-4.f * dd) + 0.25f;
        float mn = expf(-dd);
        float px = offx * dwn + gx;
        float py = offy * dwn + gy;
        float fx2 = floorf(px), fy2 = floorf(py);
        float xltx = fminf(fmaxf(fx2, 0.f), 129.f);
        float xlty = fminf(fmaxf(fy2, 0.f), 129.f);
        float xrbx = fminf(fmaxf(fx2 + 1.f, 0.f), 129.f);
        float xrby = fminf(fmaxf(fy2 + 1.f, 0.f), 129.f);
        float xpxc = fminf(fmaxf(px, 0.f), 129.f);
        float xpyc = fminf(fmaxf(py, 0.f), 129.f);
        float wlt = (1.f + (xltx - xpxc)) * (1.f + (xlty - xpyc));
        float wrb = (1.f - (xrbx - xpxc)) * (1.f - (xrby - xpyc));
        float wlb = (1.f + (xltx - xpxc)) * (1.f - (xrby - xpyc));
        float wrt = (1.f - (xrbx - xpxc)) * (1.f + (xlty - xpyc));
        int jlx = (int)xltx, jly = (int)xlty, jrx = (int)xrbx, jry = (int)xrby;
        float* d = pmw + (l15 * 9 + n) * 8;
        int* di = (int*)(d + 4);
        auto mk = [&](int qx, int qy, float gw, int slot) {
            bool ok = (qx >= 1 && qx <= 128 && qy >= 1 && qy <= 128);
            d[slot] = ok ? gw * mn : 0.f;
            int idx = 0;
            if (ok) {
                int r = qx - 1, c = qy - 1;
                int wr = r - (i - 3), wc = c - (j0 - 3);
                idx = ((unsigned)wr < 7u && (unsigned)wc < 22u) ? (wr * 22 + wc)
                                                                : (-1 - (r * 128 + c));
            }
            di[slot] = idx;
        };
        mk(jlx, jly, wlt, 0);
        mk(jrx, jry, wrb, 1);
        mk(jlx, jry, wlb, 2);
        mk(jrx, jly, wrt, 3);
    }
    __syncthreads();

    // ---- phase 2: gather from LDS window -> register B-frags -> MFMA; n%2==wv ----
    f32x4 A0 = {0.f, 0.f, 0.f, 0.f}, A1 = {0.f, 0.f, 0.f, 0.f};
    f32x4 A2 = {0.f, 0.f, 0.f, 0.f}, A3 = {0.f, 0.f, 0.f, 0.f};
    for (int n = wv; n < 9; n += 2) {
        const float* ww = pmw + (l15 * 9 + n) * 8;
        float4 w4 = *reinterpret_cast<const float4*>(ww);
        int4 i4 = *reinterpret_cast<const int4*>(ww + 4);
#pragma unroll
        for (int half = 0; half < 2; ++half) {
            int sl = half * 4 + h;
            int co = half * 32 + h * 8;
            auto tap = [&](int idx) -> bf16x8 {
                if (idx >= 0)
                    return *reinterpret_cast<const bf16x8*>(
                        (char*)win + idx * 128 + ((sl ^ (idx & 7)) << 4));
                int gp = -1 - idx;   // ultra-rare global fallback
                return *reinterpret_cast<const bf16x8*>(xTb + ((size_t)gp << 6) + co);
            };
            bf16x8 t0 = tap(i4.x), t1 = tap(i4.y), t2 = tap(i4.z), t3 = tap(i4.w);
            union { short s[8]; bf16x8 v; } bf;
#pragma unroll
            for (int e = 0; e < 8; ++e) {
                float f = w4.x * bf2f(t0[e]) + w4.y * bf2f(t1[e]) +
                          w4.z * bf2f(t2[e]) + w4.w * bf2f(t3[e]);
                bf.s[e] = f2bf(f);
            }
            const short* wk = wK + (size_t)(((n * 2 + half) * 4 + h) * 64 + l15) * 8;
            A0 = MFMA16(*reinterpret_cast<const bf16x8*>(wk),       bf.v, A0);
            A1 = MFMA16(*reinterpret_cast<const bf16x8*>(wk + 128), bf.v, A1);
            A2 = MFMA16(*reinterpret_cast<const bf16x8*>(wk + 256), bf.v, A2);
            A3 = MFMA16(*reinterpret_cast<const bf16x8*>(wk + 384), bf.v, A3);
        }
    }
    // ---- reduce across waves + store (accred/obuf overlay dead lo/part1) ----
    if (wv == 1) {
        float* ar = accred + lane * 16;
        *reinterpret_cast<f32x4*>(ar)      = A0;
        *reinterpret_cast<f32x4*>(ar + 4)  = A1;
        *reinterpret_cast<f32x4*>(ar + 8)  = A2;
        *reinterpret_cast<f32x4*>(ar + 12) = A3;
    }
    __syncthreads();
    if (wv == 0) {
        const float* ar = accred + lane * 16;
#pragma unroll
        for (int r = 0; r < 4; ++r) {
            obuf[(h * 4 + r) * 17 + l15]      = A0[r] + ar[r];
            obuf[(16 + h * 4 + r) * 17 + l15] = A1[r] + ar[4 + r];
            obuf[(32 + h * 4 + r) * 17 + l15] = A2[r] + ar[8 + r];
            obuf[(48 + h * 4 + r) * 17 + l15] = A3[r] + ar[12 + r];
        }
    }
    __syncthreads();
#pragma unroll
    for (int r = 0; r < 8; ++r) {
        int u = (r << 7) + tid;
        int o = u >> 4, p = u & 15;
        out[((size_t)(b * 64 + o) << 14) + (i << 7) + j0 + p] = obuf[o * 17 + p];
    }
}

extern "C" void kernel_launch(void* const* d_in, const int* in_sizes, int n_in,
                              void* d_out, int out_size, void* d_ws, size_t ws_size,
                              hipStream_t stream) {
    (void)in_sizes; (void)n_in; (void)out_size; (void)ws_size;
    const float* x      = (const float*)d_in[0];
    const float* depth  = (const float*)d_in[1];
    const float* w_p    = (const float*)d_in[2];
    const float* b_p    = (const float*)d_in[3];
    const float* w_conv = (const float*)d_in[4];
    float* out = (float*)d_out;

    char* wsb = (char*)d_ws;
    short* xT   = (short*)wsb;                     // 4,194,304 B
    short* xTlo = (short*)(wsb + 4194304);         // 4,194,304 B
    short* wK   = (short*)(wsb + 8388608);         //    73,728 B
    short* wPh  = (short*)(wsb + 8462336);         //    36,864 B
    short* wPl  = (short*)(wsb + 8499200);         //    36,864 B  (total ~8.54 MB)

    hipLaunchKernelGGL(k_prep,  dim3(472),  dim3(256), 0, stream,
                       x, w_conv, w_p, xT, xTlo, wK, wPh, wPl);
    hipLaunchKernelGGL(k_fused, dim3(2048), dim3(128), 0, stream,
                       xT, xTlo, wPh, wPl, wK, depth, b_p, out);
}

// Round 9
// 49.481 us; speedup vs baseline: 1.0578x; 1.0284x over previous
//
#include <hip/hip_runtime.h>
#include <math.h>

// B=2, C=64, H=W=128, N=9, KS=3, PAD=1.
// Round 9: occupancy attack. r4-r8 were pinned at ~41-45us because resident
// waves/SIMD ~2 and same-block waves stall in lockstep (VALUBusy ~= per-wave
// busy fraction). This round: 4-wave blocks (split-K x4 over taps/samples),
// LDS cut to 24.9KB (±2 window, no lo-window, accred/obuf overlays) -> 6
// blocks/CU = 6 waves/SIMD; launch_bounds(256,6).
// Offset conv stays split-bf16 3-term MFMA (fp32-grade offsets; reference
// depth bilinear is discontinuous at coord 127 and amplifies offset error).
// k map (same for A and B packs; HW k-permutation cancels):
//   k = s*32 + h*8 + e;  t/n = s>>1;  c = (s&1)*32 + h*8 + e.
// C/D: col = lane&15 (pixel), row = h*4+reg. Verified r3-r8.

typedef __attribute__((ext_vector_type(8))) short bf16x8;
typedef __attribute__((ext_vector_type(4))) short s16x4;
typedef __attribute__((ext_vector_type(4))) float f32x4;

#define MFMA16(a, b, c) __builtin_amdgcn_mfma_f32_16x16x32_bf16((a), (b), (c), 0, 0, 0)

__device__ __forceinline__ float bf2f(short v) {
    return __uint_as_float(((unsigned)(unsigned short)v) << 16);
}
__device__ __forceinline__ short f2bf(float f) {
    unsigned u = __float_as_uint(f);
    u = u + 0x7fffu + ((u >> 16) & 1u);
    return (short)(u >> 16);
}

// ---------------- prep: LDS-transpose x -> xT/xTlo; pack wK, wPh, wPl ----------------
__global__ __launch_bounds__(256) void k_prep(const float* __restrict__ x,
                                              const float* __restrict__ w_conv,
                                              const float* __restrict__ w_p,
                                              short* __restrict__ xT,
                                              short* __restrict__ xTlo,
                                              short* __restrict__ wK,
                                              short* __restrict__ wPh,
                                              short* __restrict__ wPl) {
    __shared__ short sH[128][72];
    __shared__ short sL[128][72];
    int bid = blockIdx.x;
    int tid = threadIdx.x;
    if (bid < 256) {
        int p = tid & 127;
        int halfc = tid >> 7;
        int pix0 = bid << 7;
        int b = pix0 >> 14;
        const float* xb = x + (size_t)b * 64 * 16384 + (pix0 & 16383);
#pragma unroll
        for (int cc = 0; cc < 8; ++cc) {
            int c0 = cc * 8 + halfc * 4;
            union { short s[4]; s16x4 v; } hi, lo;
#pragma unroll
            for (int e = 0; e < 4; ++e) {
                float v = xb[(c0 + e) * 16384 + p];
                short hb = f2bf(v);
                hi.s[e] = hb;
                lo.s[e] = f2bf(v - bf2f(hb));
            }
            *reinterpret_cast<s16x4*>(&sH[p][c0]) = hi.v;
            *reinterpret_cast<s16x4*>(&sL[p][c0]) = lo.v;
        }
        __syncthreads();
        short* xTo = xT   + ((size_t)pix0 << 6);
        short* xLo = xTlo + ((size_t)pix0 << 6);
#pragma unroll
        for (int r = 0; r < 4; ++r) {
            int u = (r << 8) + tid;
            int pp = u >> 3, ch8 = u & 7;
            *reinterpret_cast<bf16x8*>(xTo + pp * 64 + ch8 * 8) =
                *reinterpret_cast<const bf16x8*>(&sH[pp][ch8 * 8]);
            *reinterpret_cast<bf16x8*>(xLo + pp * 64 + ch8 * 8) =
                *reinterpret_cast<const bf16x8*>(&sL[pp][ch8 * 8]);
        }
    } else {
        int idx = (bid - 256) * 256 + tid;
        if (idx >= 55296) return;
        if (idx < 36864) {
            int e = idx & 7, o = (idx >> 3) & 63, h = (idx >> 9) & 3, s = idx >> 11;
            int k = s * 32 + h * 8 + e;
            int n = k >> 6, c = k & 63;
            wK[idx] = f2bf(w_conv[o * 576 + c * 9 + n]);
        } else {
            int j = idx - 36864;
            int e = j & 7, m = (j >> 3) & 31, h = (j >> 8) & 3, s = j >> 10;
            int k = s * 32 + h * 8 + e;
            int t = k >> 6, c = k & 63;
            float v = (m < 18) ? w_p[m * 576 + c * 9 + t] : 0.f;
            short hb = f2bf(v);
            wPh[j] = hb;
            wPl[j] = f2bf(v - bf2f(hb));
        }
    }
}

// ---------------- fused: 256 thr = 4 waves on 16 px; split-K x4; 24.9KB LDS ----------------
__global__ __launch_bounds__(256, 6) void k_fused(const short* __restrict__ xT,
                                                  const short* __restrict__ xTlo,
                                                  const short* __restrict__ wPh,
                                                  const short* __restrict__ wPl,
                                                  const short* __restrict__ wK,
                                                  const float* __restrict__ depth,
                                                  const float* __restrict__ b_p,
                                                  float* __restrict__ out) {
    // layout (bytes):
    //   win    [0,     13440)  x hi window: 105 px (5r x 21c) x 128B, XOR-swizzled
    //   part1  [13440, 18560)  float[4][16][20]
    //   dwin   [18560, 18992)  float[105] (+pad)
    //   offs   [18992, 20272)  float[16][20]
    //   pmw    [20272, 24880)  per-(p,n): float w[4]; int idx[4] (idx<0 => global)
    //   accred overlays win    (3 waves x 1024 f32 = 12288B; win dead after ph2)
    //   obuf   overlays part1  (64x17 f32 = 4352B; part1 dead after offs)
    __shared__ __align__(16) char smem[24880];
    short* win    = (short*)smem;
    float* part1  = (float*)(smem + 13440);
    float* dwin   = (float*)(smem + 18560);
    float* offs   = (float*)(smem + 18992);
    float* pmw    = (float*)(smem + 20272);
    float* accred = (float*)smem;
    float* obuf   = (float*)(smem + 13440);

    int tid = threadIdx.x;
    int lane = tid & 63;
    int wv = tid >> 6;                      // 0..3
    int l15 = lane & 15, h = lane >> 4;
    // XCD band swizzle (bijective: 2048 = 8*256)
    int bid = blockIdx.x;
    int swz = (bid & 7) * 256 + (bid >> 3);
    int pb = swz << 4;
    int b = pb >> 14, i = (pb & 16383) >> 7, j0 = pb & 127;
    const short* xTb  = xT   + ((size_t)b << 20);
    const short* xTlb = xTlo + ((size_t)b << 20);
    const float* db = depth + (b << 14);

    // ---- stage: x hi window (5r x 21c) + depth window; coalesced ----
    for (int u = tid; u < 840; u += 256) {
        int c8 = u & 7, px = u >> 3;
        int wr = px / 21, wc = px % 21;
        int r = i - 2 + wr, c = j0 - 2 + wc;
        bf16x8 v = {0, 0, 0, 0, 0, 0, 0, 0};
        if ((unsigned)r < 128u && (unsigned)c < 128u)
            v = *reinterpret_cast<const bf16x8*>(xTb + ((size_t)(r * 128 + c) << 6) + c8 * 8);
        *reinterpret_cast<bf16x8*>((char*)win + px * 128 + ((c8 ^ (px & 7)) << 4)) = v;
    }
    if (tid < 105) {
        int wr = tid / 21, wc = tid % 21;
        int r = i - 2 + wr, c = j0 - 2 + wc;
        dwin[tid] = ((unsigned)r < 128u && (unsigned)c < 128u) ? db[r * 128 + c] : 0.f;
    }
    __syncthreads();

    // ---- phase 1: offset conv; wave wv covers taps {wv, wv+4, wv+8} ----
    f32x4 acc0 = {0.f, 0.f, 0.f, 0.f}, acc1 = {0.f, 0.f, 0.f, 0.f};
    for (int t = wv; t < 9; t += 4) {
        int wp = (t / 3 + 1) * 21 + (l15 + t % 3 + 1);
        int si = i + t / 3 - 1;
        int sj = j0 + l15 + t % 3 - 1;
        bool inb = ((unsigned)si < 128u && (unsigned)sj < 128u);
        size_t go = (size_t)(si * 128 + sj) << 6;
#pragma unroll
        for (int par = 0; par < 2; ++par) {
            int s_ = t * 2 + par;
            int c8 = par * 4 + h;
            bf16x8 bh = *reinterpret_cast<const bf16x8*>(
                (char*)win + wp * 128 + ((c8 ^ (wp & 7)) << 4));
            bf16x8 bl = {0, 0, 0, 0, 0, 0, 0, 0};
            if (inb) bl = *reinterpret_cast<const bf16x8*>(xTlb + go + c8 * 8);
            const short* wh_ = wPh + (size_t)((s_ * 4 + h) * 32 + l15) * 8;
            const short* wl_ = wPl + (size_t)((s_ * 4 + h) * 32 + l15) * 8;
            bf16x8 ah0 = *reinterpret_cast<const bf16x8*>(wh_);
            bf16x8 ah1 = *reinterpret_cast<const bf16x8*>(wh_ + 128);
            bf16x8 al0 = *reinterpret_cast<const bf16x8*>(wl_);
            bf16x8 al1 = *reinterpret_cast<const bf16x8*>(wl_ + 128);
            acc0 = MFMA16(ah0, bh, acc0);
            acc1 = MFMA16(ah1, bh, acc1);
            acc0 = MFMA16(ah0, bl, acc0);
            acc1 = MFMA16(ah1, bl, acc1);
            acc0 = MFMA16(al0, bh, acc0);
            acc1 = MFMA16(al1, bh, acc1);
        }
    }
#pragma unroll
    for (int r = 0; r < 4; ++r) {
        part1[wv * 320 + l15 * 20 + h * 4 + r] = acc0[r];
        int o1 = 16 + h * 4 + r;
        if (o1 < 18) part1[wv * 320 + l15 * 20 + o1] = acc1[r];
    }
    __syncthreads();
    if (tid < 128) {
        for (int u = tid; u < 288; u += 128) {
            int p = u / 18, o = u % 18;
            offs[p * 20 + o] = part1[p * 20 + o] + part1[320 + p * 20 + o] +
                               part1[640 + p * 20 + o] + part1[960 + p * 20 + o] + b_p[o];
        }
    }
    __syncthreads();

    // ---- epilogue: group g = wv*4+h (<9) handles (p=l15, n=g); 1 unit/lane ----
    int g = (wv << 2) + h;
    if (g < 9) {
        int n = g;
        float offx = offs[l15 * 20 + n];
        float offy = offs[l15 * 20 + 9 + n];
        float gx = (float)(n / 3 - 1 + i + 1);
        float gy = (float)(n % 3 - 1 + j0 + l15 + 1);
        float dctr = dwin[2 * 21 + l15 + 2];
        float p1x = offx + gx, p1y = offy + gy;
        float fx = floorf(p1x), fy = floorf(p1y);
        float qltx = fminf(fmaxf(fx, 0.f), 127.f);
        float qlty = fminf(fmaxf(fy, 0.f), 127.f);
        float qrbx = fminf(fmaxf(fx + 1.f, 0.f), 127.f);
        float qrby = fminf(fmaxf(fy + 1.f, 0.f), 127.f);
        float pxc = fminf(fmaxf(p1x, 0.f), 127.f);
        float pyc = fminf(fmaxf(p1y, 0.f), 127.f);
        float glt = (1.f + (qltx - pxc)) * (1.f + (qlty - pyc));
        float grb = (1.f - (qrbx - pxc)) * (1.f - (qrby - pyc));
        float glb = (1.f + (qltx - pxc)) * (1.f - (qrby - pyc));
        float grt = (1.f - (qrbx - pxc)) * (1.f + (qlty - pyc));
        int ilx = (int)qltx, ily = (int)qlty, irx = (int)qrbx, iry = (int)qrby;
        auto dv = [&](int qx, int qy) -> float {
            if (qx < 1 || qx > 128 || qy < 1 || qy > 128) return 0.f;
            int r = qx - 1, c = qy - 1;
            int wr = r - (i - 2), wc = c - (j0 - 2);
            if ((unsigned)wr < 5u && (unsigned)wc < 21u) return dwin[wr * 21 + wc];
            return db[r * 128 + c];   // rare fallback
        };
        float dof = glt * dv(ilx, ily) + grb * dv(irx, iry) + glb * dv(ilx, iry) + grt * dv(irx, ily);
        float dd = fabsf(dctr - dof);
        float dwn = expf(-4.f * dd) + 0.25f;
        float mn = expf(-dd);
        float px = offx * dwn + gx;
        float py = offy * dwn + gy;
        float fx2 = floorf(px), fy2 = floorf(py);
        float xltx = fminf(fmaxf(fx2, 0.f), 129.f);
        float xlty = fminf(fmaxf(fy2, 0.f), 129.f);
        float xrbx = fminf(fmaxf(fx2 + 1.f, 0.f), 129.f);
        float xrby = fminf(fmaxf(fy2 + 1.f, 0.f), 129.f);
        float xpxc = fminf(fmaxf(px, 0.f), 129.f);
        float xpyc = fminf(fmaxf(py, 0.f), 129.f);
        float wlt = (1.f + (xltx - xpxc)) * (1.f + (xlty - xpyc));
        float wrb = (1.f - (xrbx - xpxc)) * (1.f - (xrby - xpyc));
        float wlb = (1.f + (xltx - xpxc)) * (1.f - (xrby - xpyc));
        float wrt = (1.f - (xrbx - xpxc)) * (1.f + (xlty - xpyc));
        int jlx = (int)xltx, jly = (int)xlty, jrx = (int)xrbx, jry = (int)xrby;
        float* d = pmw + (l15 * 9 + n) * 8;
        int* di = (int*)(d + 4);
        auto mk = [&](int qx, int qy, float gw, int slot) {
            bool ok = (qx >= 1 && qx <= 128 && qy >= 1 && qy <= 128);
            d[slot] = ok ? gw * mn : 0.f;
            int idx = 0;
            if (ok) {
                int r = qx - 1, c = qy - 1;
                int wr = r - (i - 2), wc = c - (j0 - 2);
                idx = ((unsigned)wr < 5u && (unsigned)wc < 21u) ? (wr * 21 + wc)
                                                                : (-1 - (r * 128 + c));
            }
            di[slot] = idx;
        };
        mk(jlx, jly, wlt, 0);
        mk(jrx, jry, wrb, 1);
        mk(jlx, jry, wlb, 2);
        mk(jrx, jly, wrt, 3);
    }
    __syncthreads();

    // ---- phase 2: wave wv covers samples {wv, wv+4, wv+8} ----
    f32x4 A0 = {0.f, 0.f, 0.f, 0.f}, A1 = {0.f, 0.f, 0.f, 0.f};
    f32x4 A2 = {0.f, 0.f, 0.f, 0.f}, A3 = {0.f, 0.f, 0.f, 0.f};
    for (int n = wv; n < 9; n += 4) {
        const float* ww = pmw + (l15 * 9 + n) * 8;
        float4 w4 = *reinterpret_cast<const float4*>(ww);
        int4 i4 = *reinterpret_cast<const int4*>(ww + 4);
#pragma unroll
        for (int half = 0; half < 2; ++half) {
            int sl = half * 4 + h;
            int co = half * 32 + h * 8;
            auto tap = [&](int idx) -> bf16x8 {
                if (idx >= 0)
                    return *reinterpret_cast<const bf16x8*>(
                        (char*)win + idx * 128 + ((sl ^ (idx & 7)) << 4));
                int gp = -1 - idx;   // rare global fallback
                return *reinterpret_cast<const bf16x8*>(xTb + ((size_t)gp << 6) + co);
            };
            bf16x8 t0 = tap(i4.x), t1 = tap(i4.y), t2 = tap(i4.z), t3 = tap(i4.w);
            union { short s[8]; bf16x8 v; } bf;
#pragma unroll
            for (int e = 0; e < 8; ++e) {
                float f = w4.x * bf2f(t0[e]) + w4.y * bf2f(t1[e]) +
                          w4.z * bf2f(t2[e]) + w4.w * bf2f(t3[e]);
                bf.s[e] = f2bf(f);
            }
            const short* wk = wK + (size_t)(((n * 2 + half) * 4 + h) * 64 + l15) * 8;
            A0 = MFMA16(*reinterpret_cast<const bf16x8*>(wk),       bf.v, A0);
            A1 = MFMA16(*reinterpret_cast<const bf16x8*>(wk + 128), bf.v, A1);
            A2 = MFMA16(*reinterpret_cast<const bf16x8*>(wk + 256), bf.v, A2);
            A3 = MFMA16(*reinterpret_cast<const bf16x8*>(wk + 384), bf.v, A3);
        }
    }
    __syncthreads();   // win dead -> accred may overlay
    if (wv != 0) {
        float* ar = accred + (wv - 1) * 1024 + lane * 16;
        *reinterpret_cast<f32x4*>(ar)      = A0;
        *reinterpret_cast<f32x4*>(ar + 4)  = A1;
        *reinterpret_cast<f32x4*>(ar + 8)  = A2;
        *reinterpret_cast<f32x4*>(ar + 12) = A3;
    }
    __syncthreads();
    if (wv == 0) {
        const float* a1 = accred + lane * 16;
        const float* a2 = accred + 1024 + lane * 16;
        const float* a3 = accred + 2048 + lane * 16;
#pragma unroll
        for (int r = 0; r < 4; ++r) {
            obuf[(h * 4 + r) * 17 + l15]      = A0[r] + a1[r] + a2[r] + a3[r];
            obuf[(16 + h * 4 + r) * 17 + l15] = A1[r] + a1[4 + r] + a2[4 + r] + a3[4 + r];
            obuf[(32 + h * 4 + r) * 17 + l15] = A2[r] + a1[8 + r] + a2[8 + r] + a3[8 + r];
            obuf[(48 + h * 4 + r) * 17 + l15] = A3[r] + a1[12 + r] + a2[12 + r] + a3[12 + r];
        }
    }
    __syncthreads();
#pragma unroll
    for (int r = 0; r < 4; ++r) {
        int u = (r << 8) + tid;
        int o = u >> 4, p = u & 15;
        out[((size_t)(b * 64 + o) << 14) + (i << 7) + j0 + p] = obuf[o * 17 + p];
    }
}

extern "C" void kernel_launch(void* const* d_in, const int* in_sizes, int n_in,
                              void* d_out, int out_size, void* d_ws, size_t ws_size,
                              hipStream_t stream) {
    (void)in_sizes; (void)n_in; (void)out_size; (void)ws_size;
    const float* x      = (const float*)d_in[0];
    const float* depth  = (const float*)d_in[1];
    const float* w_p    = (const float*)d_in[2];
    const float* b_p    = (const float*)d_in[3];
    const float* w_conv = (const float*)d_in[4];
    float* out = (float*)d_out;

    char* wsb = (char*)d_ws;
    short* xT   = (short*)wsb;                     // 4,194,304 B
    short* xTlo = (short*)(wsb + 4194304);         // 4,194,304 B
    short* wK   = (short*)(wsb + 8388608);         //    73,728 B
    short* wPh  = (short*)(wsb + 8462336);         //    36,864 B
    short* wPl  = (short*)(wsb + 8499200);         //    36,864 B  (total ~8.54 MB)

    hipLaunchKernelGGL(k_prep,  dim3(472),  dim3(256), 0, stream,
                       x, w_conv, w_p, xT, xTlo, wK, wPh, wPl);
    hipLaunchKernelGGL(k_fused, dim3(2048), dim3(256), 0, stream,
                       xT, xTlo, wPh, wPl, wK, depth, b_p, out);
}

// Round 10
// 42.410 us; speedup vs baseline: 1.2341x; 1.1667x over previous
//
#include <hip/hip_runtime.h>
#include <math.h>

// B=2, C=64, H=W=128, N=9, KS=3, PAD=1.
// Round 10: (a) fix r9's compiler spill (launch_bounds(256,6) -> 40 VGPR + 20MB
// scratch traffic; now (256,4) = 128 VGPR cap); (b) weights-after-MFMA: phase 2
// feeds RAW bf16 taps from the LDS window straight into MFMA (no per-channel
// fp32 combine / f2bf repack -- that was ~10us of chip-wide VALU on the
// LDS->MFMA critical path). Per tap t: D = mfma(wk_h0,tap_h0,0);
// D = mfma(wk_h1,tap_h1,D); A += w_t(n,p) * D  (w is per-lane scalar since
// C/D col = lane&15 = pixel). Exact linear reorder; drops one bf16 rounding.
// Offset conv stays split-bf16 3-term MFMA (fp32-grade offsets; reference
// depth bilinear is discontinuous at coord 127 and amplifies offset error).
// k map (same for A and B packs; HW k-permutation cancels):
//   k = s*32 + h*8 + e;  t/n = s>>1;  c = (s&1)*32 + h*8 + e.
// C/D: col = lane&15 (pixel), row = h*4+reg. Verified r3-r9.

typedef __attribute__((ext_vector_type(8))) short bf16x8;
typedef __attribute__((ext_vector_type(4))) short s16x4;
typedef __attribute__((ext_vector_type(4))) float f32x4;

#define MFMA16(a, b, c) __builtin_amdgcn_mfma_f32_16x16x32_bf16((a), (b), (c), 0, 0, 0)

__device__ __forceinline__ float bf2f(short v) {
    return __uint_as_float(((unsigned)(unsigned short)v) << 16);
}
__device__ __forceinline__ short f2bf(float f) {
    unsigned u = __float_as_uint(f);
    u = u + 0x7fffu + ((u >> 16) & 1u);
    return (short)(u >> 16);
}

// ---------------- prep: LDS-transpose x -> xT/xTlo; pack wK, wPh, wPl ----------------
__global__ __launch_bounds__(256) void k_prep(const float* __restrict__ x,
                                              const float* __restrict__ w_conv,
                                              const float* __restrict__ w_p,
                                              short* __restrict__ xT,
                                              short* __restrict__ xTlo,
                                              short* __restrict__ wK,
                                              short* __restrict__ wPh,
                                              short* __restrict__ wPl) {
    __shared__ short sH[128][72];
    __shared__ short sL[128][72];
    int bid = blockIdx.x;
    int tid = threadIdx.x;
    if (bid < 256) {
        int p = tid & 127;
        int halfc = tid >> 7;
        int pix0 = bid << 7;
        int b = pix0 >> 14;
        const float* xb = x + (size_t)b * 64 * 16384 + (pix0 & 16383);
#pragma unroll
        for (int cc = 0; cc < 8; ++cc) {
            int c0 = cc * 8 + halfc * 4;
            union { short s[4]; s16x4 v; } hi, lo;
#pragma unroll
            for (int e = 0; e < 4; ++e) {
                float v = xb[(c0 + e) * 16384 + p];
                short hb = f2bf(v);
                hi.s[e] = hb;
                lo.s[e] = f2bf(v - bf2f(hb));
            }
            *reinterpret_cast<s16x4*>(&sH[p][c0]) = hi.v;
            *reinterpret_cast<s16x4*>(&sL[p][c0]) = lo.v;
        }
        __syncthreads();
        short* xTo = xT   + ((size_t)pix0 << 6);
        short* xLo = xTlo + ((size_t)pix0 << 6);
#pragma unroll
        for (int r = 0; r < 4; ++r) {
            int u = (r << 8) + tid;
            int pp = u >> 3, ch8 = u & 7;
            *reinterpret_cast<bf16x8*>(xTo + pp * 64 + ch8 * 8) =
                *reinterpret_cast<const bf16x8*>(&sH[pp][ch8 * 8]);
            *reinterpret_cast<bf16x8*>(xLo + pp * 64 + ch8 * 8) =
                *reinterpret_cast<const bf16x8*>(&sL[pp][ch8 * 8]);
        }
    } else {
        int idx = (bid - 256) * 256 + tid;
        if (idx >= 55296) return;
        if (idx < 36864) {
            int e = idx & 7, o = (idx >> 3) & 63, h = (idx >> 9) & 3, s = idx >> 11;
            int k = s * 32 + h * 8 + e;
            int n = k >> 6, c = k & 63;
            wK[idx] = f2bf(w_conv[o * 576 + c * 9 + n]);
        } else {
            int j = idx - 36864;
            int e = j & 7, m = (j >> 3) & 31, h = (j >> 8) & 3, s = j >> 10;
            int k = s * 32 + h * 8 + e;
            int t = k >> 6, c = k & 63;
            float v = (m < 18) ? w_p[m * 576 + c * 9 + t] : 0.f;
            short hb = f2bf(v);
            wPh[j] = hb;
            wPl[j] = f2bf(v - bf2f(hb));
        }
    }
}

// ---------------- fused: 256 thr = 4 waves on 16 px; raw-tap MFMA phase 2 ----------------
__global__ __launch_bounds__(256, 4) void k_fused(const short* __restrict__ xT,
                                                  const short* __restrict__ xTlo,
                                                  const short* __restrict__ wPh,
                                                  const short* __restrict__ wPl,
                                                  const short* __restrict__ wK,
                                                  const float* __restrict__ depth,
                                                  const float* __restrict__ b_p,
                                                  float* __restrict__ out) {
    // layout (bytes):
    //   win    [0,     13440)  x hi window: 105 px (5r x 21c) x 128B, XOR-swizzled
    //   part1  [13440, 18560)  float[4][16][20]
    //   dwin   [18560, 18992)  float[105] (+pad)
    //   offs   [18992, 20272)  float[16][20]
    //   pmw    [20272, 24880)  per-(p,n): float w[4]; int idx[4] (idx<0 => global)
    //   accred overlays win    (3 waves x 1024 f32 = 12288B; win dead after ph2)
    //   obuf   overlays part1  (64x17 f32 = 4352B; part1 dead after offs)
    __shared__ __align__(16) char smem[24880];
    short* win    = (short*)smem;
    float* part1  = (float*)(smem + 13440);
    float* dwin   = (float*)(smem + 18560);
    float* offs   = (float*)(smem + 18992);
    float* pmw    = (float*)(smem + 20272);
    float* accred = (float*)smem;
    float* obuf   = (float*)(smem + 13440);

    int tid = threadIdx.x;
    int lane = tid & 63;
    int wv = tid >> 6;                      // 0..3
    int l15 = lane & 15, h = lane >> 4;
    // XCD band swizzle (bijective: 2048 = 8*256)
    int bid = blockIdx.x;
    int swz = (bid & 7) * 256 + (bid >> 3);
    int pb = swz << 4;
    int b = pb >> 14, i = (pb & 16383) >> 7, j0 = pb & 127;
    const short* xTb  = xT   + ((size_t)b << 20);
    const short* xTlb = xTlo + ((size_t)b << 20);
    const float* db = depth + (b << 14);

    // ---- stage: x hi window (5r x 21c) + depth window; coalesced ----
    for (int u = tid; u < 840; u += 256) {
        int c8 = u & 7, px = u >> 3;
        int wr = px / 21, wc = px % 21;
        int r = i - 2 + wr, c = j0 - 2 + wc;
        bf16x8 v = {0, 0, 0, 0, 0, 0, 0, 0};
        if ((unsigned)r < 128u && (unsigned)c < 128u)
            v = *reinterpret_cast<const bf16x8*>(xTb + ((size_t)(r * 128 + c) << 6) + c8 * 8);
        *reinterpret_cast<bf16x8*>((char*)win + px * 128 + ((c8 ^ (px & 7)) << 4)) = v;
    }
    if (tid < 105) {
        int wr = tid / 21, wc = tid % 21;
        int r = i - 2 + wr, c = j0 - 2 + wc;
        dwin[tid] = ((unsigned)r < 128u && (unsigned)c < 128u) ? db[r * 128 + c] : 0.f;
    }
    __syncthreads();

    // ---- phase 1: offset conv; wave wv covers taps {wv, wv+4, wv+8} ----
    f32x4 acc0 = {0.f, 0.f, 0.f, 0.f}, acc1 = {0.f, 0.f, 0.f, 0.f};
    for (int t = wv; t < 9; t += 4) {
        int wp = (t / 3 + 1) * 21 + (l15 + t % 3 + 1);
        int si = i + t / 3 - 1;
        int sj = j0 + l15 + t % 3 - 1;
        bool inb = ((unsigned)si < 128u && (unsigned)sj < 128u);
        size_t go = (size_t)(si * 128 + sj) << 6;
#pragma unroll
        for (int par = 0; par < 2; ++par) {
            int s_ = t * 2 + par;
            int c8 = par * 4 + h;
            bf16x8 bh = *reinterpret_cast<const bf16x8*>(
                (char*)win + wp * 128 + ((c8 ^ (wp & 7)) << 4));
            bf16x8 bl = {0, 0, 0, 0, 0, 0, 0, 0};
            if (inb) bl = *reinterpret_cast<const bf16x8*>(xTlb + go + c8 * 8);
            const short* wh_ = wPh + (size_t)((s_ * 4 + h) * 32 + l15) * 8;
            const short* wl_ = wPl + (size_t)((s_ * 4 + h) * 32 + l15) * 8;
            bf16x8 ah0 = *reinterpret_cast<const bf16x8*>(wh_);
            bf16x8 ah1 = *reinterpret_cast<const bf16x8*>(wh_ + 128);
            bf16x8 al0 = *reinterpret_cast<const bf16x8*>(wl_);
            bf16x8 al1 = *reinterpret_cast<const bf16x8*>(wl_ + 128);
            acc0 = MFMA16(ah0, bh, acc0);
            acc1 = MFMA16(ah1, bh, acc1);
            acc0 = MFMA16(ah0, bl, acc0);
            acc1 = MFMA16(ah1, bl, acc1);
            acc0 = MFMA16(al0, bh, acc0);
            acc1 = MFMA16(al1, bh, acc1);
        }
    }
#pragma unroll
    for (int r = 0; r < 4; ++r) {
        part1[wv * 320 + l15 * 20 + h * 4 + r] = acc0[r];
        int o1 = 16 + h * 4 + r;
        if (o1 < 18) part1[wv * 320 + l15 * 20 + o1] = acc1[r];
    }
    __syncthreads();
    if (tid < 128) {
        for (int u = tid; u < 288; u += 128) {
            int p = u / 18, o = u % 18;
            offs[p * 20 + o] = part1[p * 20 + o] + part1[320 + p * 20 + o] +
                               part1[640 + p * 20 + o] + part1[960 + p * 20 + o] + b_p[o];
        }
    }
    __syncthreads();

    // ---- epilogue: group g = wv*4+h (<9) handles (p=l15, n=g) ----
    int g = (wv << 2) + h;
    if (g < 9) {
        int n = g;
        float offx = offs[l15 * 20 + n];
        float offy = offs[l15 * 20 + 9 + n];
        float gx = (float)(n / 3 - 1 + i + 1);
        float gy = (float)(n % 3 - 1 + j0 + l15 + 1);
        float dctr = dwin[2 * 21 + l15 + 2];
        float p1x = offx + gx, p1y = offy + gy;
        float fx = floorf(p1x), fy = floorf(p1y);
        float qltx = fminf(fmaxf(fx, 0.f), 127.f);
        float qlty = fminf(fmaxf(fy, 0.f), 127.f);
        float qrbx = fminf(fmaxf(fx + 1.f, 0.f), 127.f);
        float qrby = fminf(fmaxf(fy + 1.f, 0.f), 127.f);
        float pxc = fminf(fmaxf(p1x, 0.f), 127.f);
        float pyc = fminf(fmaxf(p1y, 0.f), 127.f);
        float glt = (1.f + (qltx - pxc)) * (1.f + (qlty - pyc));
        float grb = (1.f - (qrbx - pxc)) * (1.f - (qrby - pyc));
        float glb = (1.f + (qltx - pxc)) * (1.f - (qrby - pyc));
        float grt = (1.f - (qrbx - pxc)) * (1.f + (qlty - pyc));
        int ilx = (int)qltx, ily = (int)qlty, irx = (int)qrbx, iry = (int)qrby;
        auto dv = [&](int qx, int qy) -> float {
            if (qx < 1 || qx > 128 || qy < 1 || qy > 128) return 0.f;
            int r = qx - 1, c = qy - 1;
            int wr = r - (i - 2), wc = c - (j0 - 2);
            if ((unsigned)wr < 5u && (unsigned)wc < 21u) return dwin[wr * 21 + wc];
            return db[r * 128 + c];   // rare fallback
        };
        float dof = glt * dv(ilx, ily) + grb * dv(irx, iry) + glb * dv(ilx, iry) + grt * dv(irx, ily);
        float dd = fabsf(dctr - dof);
        float dwn = expf(-4.f * dd) + 0.25f;
        float mn = expf(-dd);
        float px = offx * dwn + gx;
        float py = offy * dwn + gy;
        float fx2 = floorf(px), fy2 = floorf(py);
        float xltx = fminf(fmaxf(fx2, 0.f), 129.f);
        float xlty = fminf(fmaxf(fy2, 0.f), 129.f);
        float xrbx = fminf(fmaxf(fx2 + 1.f, 0.f), 129.f);
        float xrby = fminf(fmaxf(fy2 + 1.f, 0.f), 129.f);
        float xpxc = fminf(fmaxf(px, 0.f), 129.f);
        float xpyc = fminf(fmaxf(py, 0.f), 129.f);
        float wlt = (1.f + (xltx - xpxc)) * (1.f + (xlty - xpyc));
        float wrb = (1.f - (xrbx - xpxc)) * (1.f - (xrby - xpyc));
        float wlb = (1.f + (xltx - xpxc)) * (1.f - (xrby - xpyc));
        float wrt = (1.f - (xrbx - xpxc)) * (1.f + (xlty - xpyc));
        int jlx = (int)xltx, jly = (int)xlty, jrx = (int)xrbx, jry = (int)xrby;
        float* d = pmw + (l15 * 9 + n) * 8;
        int* di = (int*)(d + 4);
        auto mk = [&](int qx, int qy, float gw, int slot) {
            bool ok = (qx >= 1 && qx <= 128 && qy >= 1 && qy <= 128);
            d[slot] = ok ? gw * mn : 0.f;
            int idx = 0;   // weight 0 kills the (valid-memory) window[0] read
            if (ok) {
                int r = qx - 1, c = qy - 1;
                int wr = r - (i - 2), wc = c - (j0 - 2);
                idx = ((unsigned)wr < 5u && (unsigned)wc < 21u) ? (wr * 21 + wc)
                                                                : (-1 - (r * 128 + c));
            }
            di[slot] = idx;
        };
        mk(jlx, jly, wlt, 0);
        mk(jrx, jry, wrb, 1);
        mk(jlx, jry, wlb, 2);
        mk(jrx, jly, wrt, 3);
    }
    __syncthreads();

    // ---- phase 2: raw-tap MFMA; wave wv covers samples {wv, wv+4, wv+8} ----
    // out[o,p] = sum_n sum_t w_t(n,p) * (sum_c wK[o,(n,c)] * tap_t[c])
    f32x4 A0 = {0.f, 0.f, 0.f, 0.f}, A1 = {0.f, 0.f, 0.f, 0.f};
    f32x4 A2 = {0.f, 0.f, 0.f, 0.f}, A3 = {0.f, 0.f, 0.f, 0.f};
    for (int n = wv; n < 9; n += 4) {
        const float* ww = pmw + (l15 * 9 + n) * 8;
        float4 w4 = *reinterpret_cast<const float4*>(ww);
        int4 i4 = *reinterpret_cast<const int4*>(ww + 4);
        const short* wk0 = wK + (size_t)((n * 8 + h) * 64 + l15) * 8;   // half 0
        const short* wk1 = wk0 + 2048;                                  // half 1
        bf16x8 a00 = *reinterpret_cast<const bf16x8*>(wk0);
        bf16x8 a01 = *reinterpret_cast<const bf16x8*>(wk0 + 128);
        bf16x8 a02 = *reinterpret_cast<const bf16x8*>(wk0 + 256);
        bf16x8 a03 = *reinterpret_cast<const bf16x8*>(wk0 + 384);
        bf16x8 a10 = *reinterpret_cast<const bf16x8*>(wk1);
        bf16x8 a11 = *reinterpret_cast<const bf16x8*>(wk1 + 128);
        bf16x8 a12 = *reinterpret_cast<const bf16x8*>(wk1 + 256);
        bf16x8 a13 = *reinterpret_cast<const bf16x8*>(wk1 + 384);
        const int* ip = &i4.x;
        const float* wp = &w4.x;
#pragma unroll
        for (int t = 0; t < 4; ++t) {
            int idx = ip[t];
            float w = wp[t];
            bf16x8 th0, th1;
            if (idx >= 0) {
                const char* base = (char*)win + idx * 128;
                th0 = *reinterpret_cast<const bf16x8*>(base + ((h ^ (idx & 7)) << 4));
                th1 = *reinterpret_cast<const bf16x8*>(base + (((4 + h) ^ (idx & 7)) << 4));
            } else {
                int gp = -1 - idx;   // rare global fallback
                const short* gb = xTb + ((size_t)gp << 6) + h * 8;
                th0 = *reinterpret_cast<const bf16x8*>(gb);
                th1 = *reinterpret_cast<const bf16x8*>(gb + 32);
            }
            f32x4 Z = {0.f, 0.f, 0.f, 0.f};
            f32x4 D0 = MFMA16(a00, th0, Z);
            f32x4 D1 = MFMA16(a01, th0, Z);
            f32x4 D2 = MFMA16(a02, th0, Z);
            f32x4 D3 = MFMA16(a03, th0, Z);
            D0 = MFMA16(a10, th1, D0);
            D1 = MFMA16(a11, th1, D1);
            D2 = MFMA16(a12, th1, D2);
            D3 = MFMA16(a13, th1, D3);
            A0 += w * D0;
            A1 += w * D1;
            A2 += w * D2;
            A3 += w * D3;
        }
    }
    __syncthreads();   // win dead -> accred may overlay
    if (wv != 0) {
        float* ar = accred + (wv - 1) * 1024 + lane * 16;
        *reinterpret_cast<f32x4*>(ar)      = A0;
        *reinterpret_cast<f32x4*>(ar + 4)  = A1;
        *reinterpret_cast<f32x4*>(ar + 8)  = A2;
        *reinterpret_cast<f32x4*>(ar + 12) = A3;
    }
    __syncthreads();
    if (wv == 0) {
        const float* a1 = accred + lane * 16;
        const float* a2 = accred + 1024 + lane * 16;
        const float* a3 = accred + 2048 + lane * 16;
#pragma unroll
        for (int r = 0; r < 4; ++r) {
            obuf[(h * 4 + r) * 17 + l15]      = A0[r] + a1[r] + a2[r] + a3[r];
            obuf[(16 + h * 4 + r) * 17 + l15] = A1[r] + a1[4 + r] + a2[4 + r] + a3[4 + r];
            obuf[(32 + h * 4 + r) * 17 + l15] = A2[r] + a1[8 + r] + a2[8 + r] + a3[8 + r];
            obuf[(48 + h * 4 + r) * 17 + l15] = A3[r] + a1[12 + r] + a2[12 + r] + a3[12 + r];
        }
    }
    __syncthreads();
#pragma unroll
    for (int r = 0; r < 4; ++r) {
        int u = (r << 8) + tid;
        int o = u >> 4, p = u & 15;
        out[((size_t)(b * 64 + o) << 14) + (i << 7) + j0 + p] = obuf[o * 17 + p];
    }
}

extern "C" void kernel_launch(void* const* d_in, const int* in_sizes, int n_in,
                              void* d_out, int out_size, void* d_ws, size_t ws_size,
                              hipStream_t stream) {
    (void)in_sizes; (void)n_in; (void)out_size; (void)ws_size;
    const float* x      = (const float*)d_in[0];
    const float* depth  = (const float*)d_in[1];
    const float* w_p    = (const float*)d_in[2];
    const float* b_p    = (const float*)d_in[3];
    const float* w_conv = (const float*)d_in[4];
    float* out = (float*)d_out;

    char* wsb = (char*)d_ws;
    short* xT   = (short*)wsb;                     // 4,194,304 B
    short* xTlo = (short*)(wsb + 4194304);         // 4,194,304 B
    short* wK   = (short*)(wsb + 8388608);         //    73,728 B
    short* wPh  = (short*)(wsb + 8462336);         //    36,864 B
    short* wPl  = (short*)(wsb + 8499200);         //    36,864 B  (total ~8.54 MB)

    hipLaunchKernelGGL(k_prep,  dim3(472),  dim3(256), 0, stream,
                       x, w_conv, w_p, xT, xTlo, wK, wPh, wPl);
    hipLaunchKernelGGL(k_fused, dim3(2048), dim3(256), 0, stream,
                       xT, xTlo, wPh, wPl, wK, depth, b_p, out);
}

// Round 11
// 37.391 us; speedup vs baseline: 1.3998x; 1.1342x over previous
//
#include <hip/hip_runtime.h>
#include <math.h>

// B=2, C=64, H=W=128, N=9, KS=3, PAD=1.
// Round 11: single-generation design. 512 blocks x 512 thr (8 waves) per 64-px
// half-row -> 2 blocks/CU, ALL blocks resident at once (kernel time ~= one
// block's critical path; r4-r10 ran ~2.7 sequential generations). Wave =
// (pixel-subtile ps 0..3) x (k-half kh). Phase 1: 9 unrolled taps/wave.
// Phase 2: raw-tap MFMA (r10's weights-after-MFMA), samples n%2==kh.
// LDS 79.4KB: +/-2 swizzled x-window (5r x 69c), depth window, part1/offs/pmw,
// accred/obuf overlays. launch_bounds(512,4) -> VGPR cap 128 (r9 spill lesson).
// Offset conv stays split-bf16 3-term MFMA (fp32-grade offsets; the reference
// depth bilinear is discontinuous at coord 127 and amplifies offset error).
// k map (same for A and B packs; HW k-permutation cancels):
//   k = s*32 + h*8 + e;  t/n = s>>1;  c = (s&1)*32 + h*8 + e.
// C/D: col = lane&15 (pixel / o-in-tile), row = h*4+reg. Verified r3-r10.

typedef __attribute__((ext_vector_type(8))) short bf16x8;
typedef __attribute__((ext_vector_type(4))) short s16x4;
typedef __attribute__((ext_vector_type(4))) float f32x4;

#define MFMA16(a, b, c) __builtin_amdgcn_mfma_f32_16x16x32_bf16((a), (b), (c), 0, 0, 0)

__device__ __forceinline__ float bf2f(short v) {
    return __uint_as_float(((unsigned)(unsigned short)v) << 16);
}
__device__ __forceinline__ short f2bf(float f) {
    unsigned u = __float_as_uint(f);
    u = u + 0x7fffu + ((u >> 16) & 1u);
    return (short)(u >> 16);
}

// ---------------- prep: LDS-transpose x -> xT/xTlo; pack wK, wPh, wPl ----------------
__global__ __launch_bounds__(256) void k_prep(const float* __restrict__ x,
                                              const float* __restrict__ w_conv,
                                              const float* __restrict__ w_p,
                                              short* __restrict__ xT,
                                              short* __restrict__ xTlo,
                                              short* __restrict__ wK,
                                              short* __restrict__ wPh,
                                              short* __restrict__ wPl) {
    __shared__ short sH[128][72];
    __shared__ short sL[128][72];
    int bid = blockIdx.x;
    int tid = threadIdx.x;
    if (bid < 256) {
        int p = tid & 127;
        int halfc = tid >> 7;
        int pix0 = bid << 7;
        int b = pix0 >> 14;
        const float* xb = x + (size_t)b * 64 * 16384 + (pix0 & 16383);
#pragma unroll
        for (int cc = 0; cc < 8; ++cc) {
            int c0 = cc * 8 + halfc * 4;
            union { short s[4]; s16x4 v; } hi, lo;
#pragma unroll
            for (int e = 0; e < 4; ++e) {
                float v = xb[(c0 + e) * 16384 + p];
                short hb = f2bf(v);
                hi.s[e] = hb;
                lo.s[e] = f2bf(v - bf2f(hb));
            }
            *reinterpret_cast<s16x4*>(&sH[p][c0]) = hi.v;
            *reinterpret_cast<s16x4*>(&sL[p][c0]) = lo.v;
        }
        __syncthreads();
        short* xTo = xT   + ((size_t)pix0 << 6);
        short* xLo = xTlo + ((size_t)pix0 << 6);
#pragma unroll
        for (int r = 0; r < 4; ++r) {
            int u = (r << 8) + tid;
            int pp = u >> 3, ch8 = u & 7;
            *reinterpret_cast<bf16x8*>(xTo + pp * 64 + ch8 * 8) =
                *reinterpret_cast<const bf16x8*>(&sH[pp][ch8 * 8]);
            *reinterpret_cast<bf16x8*>(xLo + pp * 64 + ch8 * 8) =
                *reinterpret_cast<const bf16x8*>(&sL[pp][ch8 * 8]);
        }
    } else {
        int idx = (bid - 256) * 256 + tid;
        if (idx >= 55296) return;
        if (idx < 36864) {
            int e = idx & 7, o = (idx >> 3) & 63, h = (idx >> 9) & 3, s = idx >> 11;
            int k = s * 32 + h * 8 + e;
            int n = k >> 6, c = k & 63;
            wK[idx] = f2bf(w_conv[o * 576 + c * 9 + n]);
        } else {
            int j = idx - 36864;
            int e = j & 7, m = (j >> 3) & 31, h = (j >> 8) & 3, s = j >> 10;
            int k = s * 32 + h * 8 + e;
            int t = k >> 6, c = k & 63;
            float v = (m < 18) ? w_p[m * 576 + c * 9 + t] : 0.f;
            short hb = f2bf(v);
            wPh[j] = hb;
            wPl[j] = f2bf(v - bf2f(hb));
        }
    }
}

// ---------------- fused: 512 thr = 8 waves on 64 px; single generation ----------------
__global__ __launch_bounds__(512, 4) void k_fused(const short* __restrict__ xT,
                                                  const short* __restrict__ xTlo,
                                                  const short* __restrict__ wPh,
                                                  const short* __restrict__ wPl,
                                                  const short* __restrict__ wK,
                                                  const float* __restrict__ depth,
                                                  const float* __restrict__ b_p,
                                                  float* __restrict__ out) {
    // layout (bytes):
    //   win    [0,     44160)  x hi window: 345 px (5r x 69c) x 128B, XOR-swizzled
    //   dwin   [44160, 45568)  float[345] (+pad)
    //   part1  [45568, 55808)  float[4][2][16][20]
    //   offs   [55808, 60928)  float[64][20]
    //   pmw    [60928, 79360)  per-(p,n): float w[4]; int idx[4] (idx<0 => global)
    //   accred overlays win [0,16384);  obuf overlays win [16384,33280)
    __shared__ __align__(16) char smem[79360];
    short* win    = (short*)smem;
    float* dwin   = (float*)(smem + 44160);
    float* part1  = (float*)(smem + 45568);
    float* offs   = (float*)(smem + 55808);
    float* pmw    = (float*)(smem + 60928);
    float* accred = (float*)smem;
    float* obuf   = (float*)(smem + 16384);

    int tid = threadIdx.x;
    int lane = tid & 63;
    int wv = tid >> 6;                      // 0..7
    int l15 = lane & 15, h = lane >> 4;
    int ps = wv & 3;                        // pixel subtile (16 px)
    int kh = wv >> 2;                       // k-half (ph1) / sample parity (ph2)
    int p0 = ps << 4;
    // XCD band swizzle (bijective: 512 = 8*64)
    int bid = blockIdx.x;
    int swz = (bid & 7) * 64 + (bid >> 3);
    int pb = swz << 6;                      // 64-px tile (half row)
    int b = pb >> 14, i = (pb & 16383) >> 7, j0 = pb & 127;
    const short* xTb  = xT   + ((size_t)b << 20);
    const short* xTlb = xTlo + ((size_t)b << 20);
    const float* db = depth + (b << 14);

    // ---- stage: x hi window (5r x 69c) + depth window; coalesced ----
    for (int u = tid; u < 2760; u += 512) {
        int c8 = u & 7, px = u >> 3;
        int wr = px / 69, wc = px % 69;
        int r = i - 2 + wr, c = j0 - 2 + wc;
        bf16x8 v = {0, 0, 0, 0, 0, 0, 0, 0};
        if ((unsigned)r < 128u && (unsigned)c < 128u)
            v = *reinterpret_cast<const bf16x8*>(xTb + ((size_t)(r * 128 + c) << 6) + c8 * 8);
        *reinterpret_cast<bf16x8*>((char*)win + px * 128 + ((c8 ^ (px & 7)) << 4)) = v;
    }
    for (int u = tid; u < 345; u += 512) {
        int wr = u / 69, wc = u % 69;
        int r = i - 2 + wr, c = j0 - 2 + wc;
        dwin[u] = ((unsigned)r < 128u && (unsigned)c < 128u) ? db[r * 128 + c] : 0.f;
    }
    __syncthreads();

    // ---- phase 1: offset conv; wave (ps,kh): 9 taps, channel half kh ----
    f32x4 acc0 = {0.f, 0.f, 0.f, 0.f}, acc1 = {0.f, 0.f, 0.f, 0.f};
    int c8p = kh * 4 + h;
#pragma unroll
    for (int t = 0; t < 9; ++t) {
        int s_ = t * 2 + kh;
        int wp = (t / 3 + 1) * 69 + (p0 + l15 + t % 3 + 1);
        bf16x8 bh = *reinterpret_cast<const bf16x8*>(
            (char*)win + wp * 128 + ((c8p ^ (wp & 7)) << 4));
        int si = i + t / 3 - 1;
        int sj = j0 + p0 + l15 + t % 3 - 1;
        bf16x8 bl = {0, 0, 0, 0, 0, 0, 0, 0};
        if ((unsigned)si < 128u && (unsigned)sj < 128u)
            bl = *reinterpret_cast<const bf16x8*>(
                xTlb + ((size_t)(si * 128 + sj) << 6) + c8p * 8);
        const short* wh_ = wPh + (size_t)((s_ * 4 + h) * 32 + l15) * 8;
        const short* wl_ = wPl + (size_t)((s_ * 4 + h) * 32 + l15) * 8;
        bf16x8 ah0 = *reinterpret_cast<const bf16x8*>(wh_);
        bf16x8 ah1 = *reinterpret_cast<const bf16x8*>(wh_ + 128);
        bf16x8 al0 = *reinterpret_cast<const bf16x8*>(wl_);
        bf16x8 al1 = *reinterpret_cast<const bf16x8*>(wl_ + 128);
        acc0 = MFMA16(ah0, bh, acc0);
        acc1 = MFMA16(ah1, bh, acc1);
        acc0 = MFMA16(ah0, bl, acc0);
        acc1 = MFMA16(ah1, bl, acc1);
        acc0 = MFMA16(al0, bh, acc0);
        acc1 = MFMA16(al1, bh, acc1);
    }
    {
        float* pp = part1 + ((ps * 2 + kh) * 16 + l15) * 20;
#pragma unroll
        for (int r = 0; r < 4; ++r) {
            pp[h * 4 + r] = acc0[r];
            int o1 = 16 + h * 4 + r;
            if (o1 < 18) pp[o1] = acc1[r];
        }
    }
    __syncthreads();
    for (int u = tid; u < 1152; u += 512) {
        int p = u / 18, o = u % 18;
        int pps = p >> 4, pl = p & 15;
        offs[p * 20 + o] = part1[((pps * 2) * 16 + pl) * 20 + o] +
                           part1[((pps * 2 + 1) * 16 + pl) * 20 + o] + b_p[o];
    }
    __syncthreads();

    // ---- epilogue: unit u = (p, n); depth bilinear -> pmw ----
    for (int u = tid; u < 576; u += 512) {
        int p = u / 9, n = u % 9;
        float offx = offs[p * 20 + n];
        float offy = offs[p * 20 + 9 + n];
        float gx = (float)(n / 3 - 1 + i + 1);
        float gy = (float)(n % 3 - 1 + j0 + p + 1);
        float dctr = dwin[2 * 69 + p + 2];
        float p1x = offx + gx, p1y = offy + gy;
        float fx = floorf(p1x), fy = floorf(p1y);
        float qltx = fminf(fmaxf(fx, 0.f), 127.f);
        float qlty = fminf(fmaxf(fy, 0.f), 127.f);
        float qrbx = fminf(fmaxf(fx + 1.f, 0.f), 127.f);
        float qrby = fminf(fmaxf(fy + 1.f, 0.f), 127.f);
        float pxc = fminf(fmaxf(p1x, 0.f), 127.f);
        float pyc = fminf(fmaxf(p1y, 0.f), 127.f);
        float glt = (1.f + (qltx - pxc)) * (1.f + (qlty - pyc));
        float grb = (1.f - (qrbx - pxc)) * (1.f - (qrby - pyc));
        float glb = (1.f + (qltx - pxc)) * (1.f - (qrby - pyc));
        float grt = (1.f - (qrbx - pxc)) * (1.f + (qlty - pyc));
        int ilx = (int)qltx, ily = (int)qlty, irx = (int)qrbx, iry = (int)qrby;
        auto dv = [&](int qx, int qy) -> float {
            if (qx < 1 || qx > 128 || qy < 1 || qy > 128) return 0.f;
            int r = qx - 1, c = qy - 1;
            int wr = r - (i - 2), wc = c - (j0 - 2);
            if ((unsigned)wr < 5u && (unsigned)wc < 69u) return dwin[wr * 69 + wc];
            return db[r * 128 + c];   // rare fallback
        };
        float dof = glt * dv(ilx, ily) + grb * dv(irx, iry) + glb * dv(ilx, iry) + grt * dv(irx, ily);
        float dd = fabsf(dctr - dof);
        float dwn = expf(-4.f * dd) + 0.25f;
        float mn = expf(-dd);
        float px = offx * dwn + gx;
        float py = offy * dwn + gy;
        float fx2 = floorf(px), fy2 = floorf(py);
        float xltx = fminf(fmaxf(fx2, 0.f), 129.f);
        float xlty = fminf(fmaxf(fy2, 0.f), 129.f);
        float xrbx = fminf(fmaxf(fx2 + 1.f, 0.f), 129.f);
        float xrby = fminf(fmaxf(fy2 + 1.f, 0.f), 129.f);
        float xpxc = fminf(fmaxf(px, 0.f), 129.f);
        float xpyc = fminf(fmaxf(py, 0.f), 129.f);
        float wlt = (1.f + (xltx - xpxc)) * (1.f + (xlty - xpyc));
        float wrb = (1.f - (xrbx - xpxc)) * (1.f - (xrby - xpyc));
        float wlb = (1.f + (xltx - xpxc)) * (1.f - (xrby - xpyc));
        float wrt = (1.f - (xrbx - xpxc)) * (1.f + (xlty - xpyc));
        int jlx = (int)xltx, jly = (int)xlty, jrx = (int)xrbx, jry = (int)xrby;
        float* d = pmw + u * 8;
        int* di = (int*)(d + 4);
        auto mk = [&](int qx, int qy, float gw, int slot) {
            bool ok = (qx >= 1 && qx <= 128 && qy >= 1 && qy <= 128);
            d[slot] = ok ? gw * mn : 0.f;
            int idx = 0;   // weight 0 kills the (valid) window[0] read
            if (ok) {
                int r = qx - 1, c = qy - 1;
                int wr = r - (i - 2), wc = c - (j0 - 2);
                idx = ((unsigned)wr < 5u && (unsigned)wc < 69u) ? (wr * 69 + wc)
                                                                : (-1 - (r * 128 + c));
            }
            di[slot] = idx;
        };
        mk(jlx, jly, wlt, 0);
        mk(jrx, jry, wrb, 1);
        mk(jlx, jry, wlb, 2);
        mk(jrx, jly, wrt, 3);
    }
    __syncthreads();

    // ---- phase 2: raw-tap MFMA; wave (ps,kh): samples n%2==kh for its 16 px ----
    f32x4 A0 = {0.f, 0.f, 0.f, 0.f}, A1 = {0.f, 0.f, 0.f, 0.f};
    f32x4 A2 = {0.f, 0.f, 0.f, 0.f}, A3 = {0.f, 0.f, 0.f, 0.f};
    for (int n = kh; n < 9; n += 2) {
        const float* ww = pmw + (size_t)((p0 + l15) * 9 + n) * 8;
        float4 w4 = *reinterpret_cast<const float4*>(ww);
        int4 i4 = *reinterpret_cast<const int4*>(ww + 4);
        const short* wk0 = wK + (size_t)((n * 8 + h) * 64 + l15) * 8;   // half 0
        const short* wk1 = wk0 + 2048;                                  // half 1
        bf16x8 a00 = *reinterpret_cast<const bf16x8*>(wk0);
        bf16x8 a01 = *reinterpret_cast<const bf16x8*>(wk0 + 128);
        bf16x8 a02 = *reinterpret_cast<const bf16x8*>(wk0 + 256);
        bf16x8 a03 = *reinterpret_cast<const bf16x8*>(wk0 + 384);
        bf16x8 a10 = *reinterpret_cast<const bf16x8*>(wk1);
        bf16x8 a11 = *reinterpret_cast<const bf16x8*>(wk1 + 128);
        bf16x8 a12 = *reinterpret_cast<const bf16x8*>(wk1 + 256);
        bf16x8 a13 = *reinterpret_cast<const bf16x8*>(wk1 + 384);
        const int* ip = &i4.x;
        const float* wp = &w4.x;
#pragma unroll
        for (int t = 0; t < 4; ++t) {
            int idx = ip[t];
            float w = wp[t];
            bf16x8 th0, th1;
            if (idx >= 0) {
                const char* base = (char*)win + idx * 128;
                th0 = *reinterpret_cast<const bf16x8*>(base + ((h ^ (idx & 7)) << 4));
                th1 = *reinterpret_cast<const bf16x8*>(base + (((4 + h) ^ (idx & 7)) << 4));
            } else {
                int gp = -1 - idx;   // rare global fallback
                const short* gb = xTb + ((size_t)gp << 6) + h * 8;
                th0 = *reinterpret_cast<const bf16x8*>(gb);
                th1 = *reinterpret_cast<const bf16x8*>(gb + 32);
            }
            f32x4 Z = {0.f, 0.f, 0.f, 0.f};
            f32x4 D0 = MFMA16(a00, th0, Z);
            f32x4 D1 = MFMA16(a01, th0, Z);
            f32x4 D2 = MFMA16(a02, th0, Z);
            f32x4 D3 = MFMA16(a03, th0, Z);
            D0 = MFMA16(a10, th1, D0);
            D1 = MFMA16(a11, th1, D1);
            D2 = MFMA16(a12, th1, D2);
            D3 = MFMA16(a13, th1, D3);
            A0 += w * D0;
            A1 += w * D1;
            A2 += w * D2;
            A3 += w * D3;
        }
    }
    __syncthreads();   // win dead -> accred/obuf overlays valid
    if (kh == 1) {
        float* ar = accred + (ps * 64 + lane) * 16;
        *reinterpret_cast<f32x4*>(ar)      = A0;
        *reinterpret_cast<f32x4*>(ar + 4)  = A1;
        *reinterpret_cast<f32x4*>(ar + 8)  = A2;
        *reinterpret_cast<f32x4*>(ar + 12) = A3;
    }
    __syncthreads();
    if (kh == 0) {
        const float* ar = accred + (ps * 64 + lane) * 16;
        int col = p0 + l15;
#pragma unroll
        for (int r = 0; r < 4; ++r) {
            obuf[(h * 4 + r) * 66 + col]      = A0[r] + ar[r];
            obuf[(16 + h * 4 + r) * 66 + col] = A1[r] + ar[4 + r];
            obuf[(32 + h * 4 + r) * 66 + col] = A2[r] + ar[8 + r];
            obuf[(48 + h * 4 + r) * 66 + col] = A3[r] + ar[12 + r];
        }
    }
    __syncthreads();
#pragma unroll
    for (int r = 0; r < 8; ++r) {
        int u = (r << 9) + tid;
        int o = u >> 6, p = u & 63;
        out[((size_t)(b * 64 + o) << 14) + (i << 7) + j0 + p] = obuf[o * 66 + p];
    }
}

extern "C" void kernel_launch(void* const* d_in, const int* in_sizes, int n_in,
                              void* d_out, int out_size, void* d_ws, size_t ws_size,
                              hipStream_t stream) {
    (void)in_sizes; (void)n_in; (void)out_size; (void)ws_size;
    const float* x      = (const float*)d_in[0];
    const float* depth  = (const float*)d_in[1];
    const float* w_p    = (const float*)d_in[2];
    const float* b_p    = (const float*)d_in[3];
    const float* w_conv = (const float*)d_in[4];
    float* out = (float*)d_out;

    char* wsb = (char*)d_ws;
    short* xT   = (short*)wsb;                     // 4,194,304 B
    short* xTlo = (short*)(wsb + 4194304);         // 4,194,304 B
    short* wK   = (short*)(wsb + 8388608);         //    73,728 B
    short* wPh  = (short*)(wsb + 8462336);         //    36,864 B
    short* wPl  = (short*)(wsb + 8499200);         //    36,864 B  (total ~8.54 MB)

    hipLaunchKernelGGL(k_prep,  dim3(472), dim3(256), 0, stream,
                       x, w_conv, w_p, xT, xTlo, wK, wPh, wPl);
    hipLaunchKernelGGL(k_fused, dim3(512), dim3(512), 0, stream,
                       xT, xTlo, wPh, wPl, wK, depth, b_p, out);
}